// Round 6
// baseline (247.000 us; speedup 1.0000x reference)
//
#include <hip/hip_runtime.h>
#include <cmath>

#define BB 8
#define CC 64
#define HH 128
#define WW 128

typedef short s8v __attribute__((ext_vector_type(8)));      // raw 16B move
typedef float f4v __attribute__((ext_vector_type(4)));      // 4 fp32 acc
typedef _Float16 h8 __attribute__((ext_vector_type(8)));    // 8 f16 (4 VGPRs)
typedef unsigned short u16;
typedef u16 u4v __attribute__((ext_vector_type(4)));

__device__ __forceinline__ u16 f2h(float f) {
    _Float16 h = (_Float16)f;
    return __builtin_bit_cast(u16, h);
}
__device__ __forceinline__ _Float16 h_from_bits(u16 b) {
    return __builtin_bit_cast(_Float16, b);
}

// ---------------------------------------------------------------------------
// Kernel 0: NCHW fp32 (x_vq ++ x_res) -> NHWC f16 xin[B][H][W][128]
// ---------------------------------------------------------------------------
__global__ __launch_bounds__(256)
void x2nhwc_kernel(const float* __restrict__ xvq, const float* __restrict__ xres,
                   u16* __restrict__ xout)
{
    const int h = blockIdx.x;
    const int b = blockIdx.y;
    __shared__ u16 lds[128 * 132];

    for (int i = 0; i < 16; ++i) {
        const int idx = threadIdx.x + 256 * i;       // 4096 float4
        const int c = idx >> 5;
        const int w4 = (idx & 31) * 4;
        const float* src = (c < 64)
            ? &xvq[(((size_t)b * 64 + c) * HH + h) * WW]
            : &xres[(((size_t)b * 64 + (c - 64)) * HH + h) * WW];
        const float4 v = *(const float4*)(src + w4);
        lds[(w4 + 0) * 132 + c] = f2h(v.x);
        lds[(w4 + 1) * 132 + c] = f2h(v.y);
        lds[(w4 + 2) * 132 + c] = f2h(v.z);
        lds[(w4 + 3) * 132 + c] = f2h(v.w);
    }
    __syncthreads();
    u16* orow = xout + (((size_t)b * HH + h) * WW) * 128;
    for (int i = 0; i < 16; ++i) {
        const int idx = threadIdx.x + 256 * i;       // 4096 ushort4
        const int w = idx >> 5;
        const int q = idx & 31;
        *(u4v*)(orow + (size_t)w * 128 + q * 4) = *(const u4v*)&lds[w * 132 + q * 4];
    }
}

// ---------------------------------------------------------------------------
// Fused weight transforms (fp32 -> f16).
// ---------------------------------------------------------------------------
__global__ void wfuse_kernel(const float* __restrict__ W1, const float* __restrict__ Woff,
                             const float* __restrict__ Wmod, const float* __restrict__ Wdcn,
                             u16* __restrict__ W1t, u16* __restrict__ Womt,
                             u16* __restrict__ Wdt)
{
    int idx = blockIdx.x * 256 + threadIdx.x;
    if (idx < 73728) {
        const int ic = idx & 127;
        const int oc = (idx >> 7) & 63;
        const int t  = idx >> 13;
        W1t[idx] = f2h(W1[((size_t)(oc * 128 + ic)) * 9 + t]);
        return;
    }
    idx -= 73728;
    if (idx < 18432) {
        const int c = idx & 63;
        const int o = (idx >> 6) & 31;
        const int t = idx >> 11;
        float v = 0.f;
        if (o < 18)      v = Woff[((size_t)(o * 64 + c)) * 9 + t];
        else if (o < 27) v = Wmod[((size_t)((o - 18) * 64 + c)) * 9 + t];
        Womt[idx] = f2h(v);
        return;
    }
    idx -= 18432;
    if (idx < 36864) {
        const int c  = idx & 63;
        const int oc = (idx >> 6) & 63;
        const int k  = idx >> 12;
        Wdt[idx] = f2h(Wdcn[((size_t)(oc * 64 + c)) * 9 + k]);
    }
}

// ---------------------------------------------------------------------------
// Kernel A: conv1 implicit-GEMM f16 MFMA. 16x16 px x 64 oc per block.
// Input tile in LDS (32-ic chunks); B-fragments loaded straight from global
// (L2-hot, identical across blocks) -> LDS 23.3 KB, 6 blocks/CU.
// ---------------------------------------------------------------------------
__global__ __launch_bounds__(256)
void conv1_mfma_kernel(const u16* __restrict__ xin, const u16* __restrict__ W1t,
                       const float* __restrict__ b1, u16* __restrict__ feath)
{
    __shared__ u16 sTile[324 * 36];   // [18x18][ic32 pad36] 23.3 KB

    const int x0 = blockIdx.x * 16;
    const int y0 = blockIdx.y * 16;
    const int b  = blockIdx.z;
    const int tid = threadIdx.x;
    const int lane = tid & 63;
    const int wave = tid >> 6;
    const int lm = lane & 15;
    const int kg = lane >> 4;

    const u16* xb = xin + ((size_t)b * HH * WW) * 128;

    f4v acc[4][4];
#pragma unroll
    for (int i = 0; i < 4; ++i)
#pragma unroll
        for (int j = 0; j < 4; ++j) acc[i][j] = (f4v)0.f;

    for (int chunk = 0; chunk < 4; ++chunk) {
        const int c0 = chunk * 32;
        __syncthreads();
        for (int i = 0; i < 6; ++i) {
            const int idx = tid + 256 * i;
            if (idx < 1296) {
                const int pix = idx >> 2;
                const int q   = idx & 3;
                const int gy = y0 - 1 + pix / 18;
                const int gx = x0 - 1 + pix % 18;
                s8v v = (s8v)0;
                if ((unsigned)gy < HH && (unsigned)gx < WW)
                    v = *(const s8v*)(xb + ((size_t)(gy * WW + gx)) * 128 + c0 + q * 8);
                *(s8v*)&sTile[pix * 36 + q * 8] = v;
            }
        }
        __syncthreads();

#pragma unroll
        for (int t = 0; t < 9; ++t) {
            const int dy = t / 3, dx = t % 3;
            h8 a[4], bq[4];
            // B-fragments straight from global (L2-hot)
#pragma unroll
            for (int nt = 0; nt < 4; ++nt) {
                const int oc = nt * 16 + lm;
                bq[nt] = *(const h8*)(W1t + ((size_t)(t * 64 + oc)) * 128 + c0 + kg * 8);
            }
#pragma unroll
            for (int mt = 0; mt < 4; ++mt) {
                const int p = wave * 64 + mt * 16 + lm;
                const int sidx = ((p >> 4) + dy) * 18 + (p & 15) + dx;
                a[mt] = *(const h8*)&sTile[sidx * 36 + kg * 8];
            }
#pragma unroll
            for (int mt = 0; mt < 4; ++mt)
#pragma unroll
                for (int nt = 0; nt < 4; ++nt)
                    acc[mt][nt] = __builtin_amdgcn_mfma_f32_16x16x32_f16(
                        a[mt], bq[nt], acc[mt][nt], 0, 0, 0);
        }
    }

#pragma unroll
    for (int nt = 0; nt < 4; ++nt) {
        const int oc = nt * 16 + lm;
        const float bias = b1[oc];
#pragma unroll
        for (int mt = 0; mt < 4; ++mt)
#pragma unroll
            for (int r = 0; r < 4; ++r) {
                const int p = wave * 64 + mt * 16 + kg * 4 + r;
                const int y = y0 + (p >> 4), x = x0 + (p & 15);
                feath[(((size_t)b * HH + y) * WW + x) * CC + oc] =
                    f2h(acc[mt][nt][r] + bias);
            }
    }
}

// ---------------------------------------------------------------------------
// Kernel B: offset+mod conv, 16x16 px x 32(27) out per block, f16 MFMA.
// B-fragments from global; only the input tile in LDS.
// ---------------------------------------------------------------------------
__global__ __launch_bounds__(256)
void offmod_mfma_kernel(const u16* __restrict__ feath, const u16* __restrict__ Womt,
                        const float* __restrict__ boff, const float* __restrict__ bmod,
                        float* __restrict__ om)
{
    __shared__ u16 sTile[324 * 36];   // [18x18][c32 pad36] 23.3 KB

    const int x0 = blockIdx.x * 16;
    const int y0 = blockIdx.y * 16;
    const int b  = blockIdx.z;
    const int tid = threadIdx.x;
    const int lane = tid & 63;
    const int wave = tid >> 6;
    const int lm = lane & 15;
    const int kg = lane >> 4;

    const u16* fb = feath + ((size_t)b * HH * WW) * CC;

    f4v acc[4][2];
#pragma unroll
    for (int i = 0; i < 4; ++i)
#pragma unroll
        for (int j = 0; j < 2; ++j) acc[i][j] = (f4v)0.f;

    for (int chunk = 0; chunk < 2; ++chunk) {
        const int c0 = chunk * 32;
        __syncthreads();
        for (int i = 0; i < 6; ++i) {
            const int idx = tid + 256 * i;
            if (idx < 1296) {
                const int pix = idx >> 2;
                const int q   = idx & 3;
                const int gy = y0 - 1 + pix / 18;
                const int gx = x0 - 1 + pix % 18;
                s8v v = (s8v)0;
                if ((unsigned)gy < HH && (unsigned)gx < WW)
                    v = *(const s8v*)(fb + ((size_t)(gy * WW + gx)) * CC + c0 + q * 8);
                *(s8v*)&sTile[pix * 36 + q * 8] = v;
            }
        }
        __syncthreads();

#pragma unroll
        for (int t = 0; t < 9; ++t) {
            const int dy = t / 3, dx = t % 3;
            h8 a[4], bq[2];
#pragma unroll
            for (int nt = 0; nt < 2; ++nt) {
                const int o = nt * 16 + lm;
                bq[nt] = *(const h8*)(Womt + ((size_t)(t * 32 + o)) * 64 + c0 + kg * 8);
            }
#pragma unroll
            for (int mt = 0; mt < 4; ++mt) {
                const int p = wave * 64 + mt * 16 + lm;
                const int sidx = ((p >> 4) + dy) * 18 + (p & 15) + dx;
                a[mt] = *(const h8*)&sTile[sidx * 36 + kg * 8];
            }
#pragma unroll
            for (int mt = 0; mt < 4; ++mt)
#pragma unroll
                for (int nt = 0; nt < 2; ++nt)
                    acc[mt][nt] = __builtin_amdgcn_mfma_f32_16x16x32_f16(
                        a[mt], bq[nt], acc[mt][nt], 0, 0, 0);
        }
    }

#pragma unroll
    for (int nt = 0; nt < 2; ++nt) {
        const int o = nt * 16 + lm;
        if (o >= 27) continue;
#pragma unroll
        for (int mt = 0; mt < 4; ++mt)
#pragma unroll
            for (int r = 0; r < 4; ++r) {
                const int p = wave * 64 + mt * 16 + kg * 4 + r;
                const int y = y0 + (p >> 4), x = x0 + (p & 15);
                float* op = om + (((size_t)b * HH + y) * WW + x) * 27;
                if (o < 18) op[o] = acc[mt][nt][r] + boff[o];
                else {
                    const float z = acc[mt][nt][r] + bmod[o - 18];
                    op[o] = 2.f / (1.f + expf(-z));
                }
            }
    }
}

// ---------------------------------------------------------------------------
// Kernel C: deformable sampling + modulated einsum, f16, software-pipelined.
// Corner loads for tap k+1 issue right after barrier k (consumed next iter);
// sV double-buffered -> 1 barrier per tap; Wd B-fragments from global.
// ---------------------------------------------------------------------------
__global__ __launch_bounds__(256)
void dcn_mfma_kernel(const u16* __restrict__ feath, const float* __restrict__ om,
                     const u16* __restrict__ Wdt, const float* __restrict__ bdcn,
                     float* __restrict__ out)
{
    __shared__ u16 sV[2][64 * 72];    // double-buffered [p][c64 pad72] 18.4 KB
    __shared__ float sOm[64 * 28];    // [p][27 pad28] 7.2 KB
    __shared__ int sOffs[576 * 4];    // [k*64+p][corner] 9.2 KB
    __shared__ u16 sWts[576 * 4];     // [k*64+p][corner] f16 w*mod 4.6 KB

    const int b  = blockIdx.z;
    const int x0 = blockIdx.x * 8;
    const int y0 = blockIdx.y * 8;
    const int tid = threadIdx.x;
    const int lane = tid & 63;
    const int wave = tid >> 6;
    const int wi = wave >> 1;
    const int wj = wave & 1;
    const int lm = lane & 15;
    const int kg = lane >> 4;

    for (int idx = tid; idx < 64 * 27; idx += 256) {
        const int p = idx / 27;
        const int j = idx - p * 27;
        const int y = y0 + (p >> 3), x = x0 + (p & 7);
        sOm[p * 28 + j] = om[(((size_t)b * HH + y) * WW + x) * 27 + j];
    }
    __syncthreads();

    // ---- precompute bilinear records (mod folded into corner weights) ----
    for (int idx = tid; idx < 576; idx += 256) {
        const int p = idx & 63, k = idx >> 6;
        const int yy = y0 + (p >> 3), xx = x0 + (p & 7);
        const float dy = sOm[p * 28 + 2 * k];
        const float dx = sOm[p * 28 + 2 * k + 1];
        const float m  = sOm[p * 28 + 18 + k];
        const float pyf = (float)(yy + (k / 3) - 1) + dy;
        const float pxf = (float)(xx + (k % 3) - 1) + dx;
        const float fy0 = floorf(pyf), fx0 = floorf(pxf);
        const float wy1 = pyf - fy0, wx1 = pxf - fx0;
        const int iy0 = (int)fy0, ix0 = (int)fx0;
        const float w[4] = { m * (1.f - wy1) * (1.f - wx1), m * (1.f - wy1) * wx1,
                             m * wy1 * (1.f - wx1),         m * wy1 * wx1 };
        const int ys[4] = { iy0, iy0, iy0 + 1, iy0 + 1 };
        const int xs[4] = { ix0, ix0 + 1, ix0, ix0 + 1 };
#pragma unroll
        for (int cn = 0; cn < 4; ++cn) {
            const bool valid = ((unsigned)ys[cn] < (unsigned)HH) &&
                               ((unsigned)xs[cn] < (unsigned)WW);
            sOffs[idx * 4 + cn] = valid ? (ys[cn] * WW + xs[cn]) * CC : 0;
            sWts[idx * 4 + cn]  = f2h(valid ? w[cn] : 0.f);
        }
    }
    __syncthreads();   // records written by other threads

    const int p1 = tid >> 2;
    const int cb = (tid & 3) * 16;

    f4v acc[2][2];
#pragma unroll
    for (int i = 0; i < 2; ++i)
#pragma unroll
        for (int j = 0; j < 2; ++j) acc[i][j] = (f4v)0.f;

    const u16* fb = feath + ((size_t)b * HH * WW) * CC;

    h8 cr[8];        // prefetched corner data (4 corners x 16 ch)
    u4v wt4;

    auto load_gather = [&](int k) {
        const int rec = (k * 64 + p1) * 4;
        const int4 off4 = *(const int4*)&sOffs[rec];
        wt4 = *(const u4v*)&sWts[rec];
        const u16* c0p = fb + off4.x + cb;
        const u16* c1p = fb + off4.y + cb;
        const u16* c2p = fb + off4.z + cb;
        const u16* c3p = fb + off4.w + cb;
        cr[0] = *(const h8*)c0p; cr[1] = *(const h8*)(c0p + 8);
        cr[2] = *(const h8*)c1p; cr[3] = *(const h8*)(c1p + 8);
        cr[4] = *(const h8*)c2p; cr[5] = *(const h8*)(c2p + 8);
        cr[6] = *(const h8*)c3p; cr[7] = *(const h8*)(c3p + 8);
    };

    load_gather(0);

    for (int k = 0; k < 9; ++k) {
        // ---- blend (consumes cr/wt4 prefetched last iteration) ----
        h8 w8 = (h8)h_from_bits(wt4.x);
        h8 a0 = w8 * cr[0];
        h8 a1 = w8 * cr[1];
        w8 = (h8)h_from_bits(wt4.y);
        a0 += w8 * cr[2]; a1 += w8 * cr[3];
        w8 = (h8)h_from_bits(wt4.z);
        a0 += w8 * cr[4]; a1 += w8 * cr[5];
        w8 = (h8)h_from_bits(wt4.w);
        a0 += w8 * cr[6]; a1 += w8 * cr[7];

        u16* vbuf = sV[k & 1];
        *(h8*)&vbuf[p1 * 72 + cb]     = a0;
        *(h8*)&vbuf[p1 * 72 + cb + 8] = a1;

        __syncthreads();

        // ---- prefetch next tap's corners (overlaps GEMM below) ----
        if (k < 8) load_gather(k + 1);

        // ---- GEMM: acc += V[64p][64c] * Wd_k[64c][64oc] ----
        h8 a[2][2], bf[2][2];
#pragma unroll
        for (int nt = 0; nt < 2; ++nt) {
            const int oc = wj * 32 + nt * 16 + lm;
#pragma unroll
            for (int ks = 0; ks < 2; ++ks)
                bf[nt][ks] = *(const h8*)(Wdt + ((size_t)(k * 64 + oc)) * 64 +
                                          ks * 32 + kg * 8);
        }
#pragma unroll
        for (int mt = 0; mt < 2; ++mt) {
            const int p = wi * 32 + mt * 16 + lm;
#pragma unroll
            for (int ks = 0; ks < 2; ++ks)
                a[mt][ks] = *(const h8*)&vbuf[p * 72 + ks * 32 + kg * 8];
        }
#pragma unroll
        for (int mt = 0; mt < 2; ++mt)
#pragma unroll
            for (int nt = 0; nt < 2; ++nt)
#pragma unroll
                for (int ks = 0; ks < 2; ++ks)
                    acc[mt][nt] = __builtin_amdgcn_mfma_f32_16x16x32_f16(
                        a[mt][ks], bf[nt][ks], acc[mt][nt], 0, 0, 0);
    }

    // epilogue: NCHW fp32
#pragma unroll
    for (int mt = 0; mt < 2; ++mt)
#pragma unroll
        for (int nt = 0; nt < 2; ++nt) {
            const int oc = wj * 32 + nt * 16 + lm;
            const float bias = bdcn[oc];
#pragma unroll
            for (int r = 0; r < 4; ++r) {
                const int p = wi * 32 + mt * 16 + kg * 4 + r;
                const int y = y0 + (p >> 3), x = x0 + (p & 7);
                out[(((size_t)b * CC + oc) * HH + y) * WW + x] = acc[mt][nt][r] + bias;
            }
        }
}

extern "C" void kernel_launch(void* const* d_in, const int* in_sizes, int n_in,
                              void* d_out, int out_size, void* d_ws, size_t ws_size,
                              hipStream_t stream)
{
    const float* xvq  = (const float*)d_in[0];
    const float* xres = (const float*)d_in[1];
    const float* W1   = (const float*)d_in[2];
    const float* b1   = (const float*)d_in[3];
    const float* Woff = (const float*)d_in[4];
    const float* boff = (const float*)d_in[5];
    const float* Wmod = (const float*)d_in[6];
    const float* bmod = (const float*)d_in[7];
    const float* Wdcn = (const float*)d_in[8];
    const float* bdcn = (const float*)d_in[9];
    float* out = (float*)d_out;

    u16*  feath = (u16*)d_ws;                              // 8.39M u16
    float* om   = (float*)(feath + (size_t)BB * HH * WW * CC);  // 3.54M f32
    u16*  xin   = (u16*)(om + (size_t)BB * HH * WW * 27);  // 16.78M u16
    u16*  W1t   = xin + (size_t)BB * HH * WW * 128;        // 73728 u16
    u16*  Womt  = W1t + 9 * 64 * 128;                      // 18432 u16
    u16*  Wdt   = Womt + 9 * 32 * 64;                      // 36864 u16

    x2nhwc_kernel<<<dim3(HH, BB), 256, 0, stream>>>(xvq, xres, xin);
    wfuse_kernel<<<dim3(504), 256, 0, stream>>>(W1, Woff, Wmod, Wdcn, W1t, Womt, Wdt);
    conv1_mfma_kernel<<<dim3(8, 8, 8), 256, 0, stream>>>(xin, W1t, b1, feath);
    offmod_mfma_kernel<<<dim3(8, 8, 8), 256, 0, stream>>>(feath, Womt, boff, bmod, om);
    dcn_mfma_kernel<<<dim3(16, 16, 8), 256, 0, stream>>>(feath, om, Wdt, bdcn, out);
}

// Round 7
// 218.172 us; speedup vs baseline: 1.1321x; 1.1321x over previous
//
#include <hip/hip_runtime.h>
#include <cmath>

#define BB 8
#define CC 64
#define HH 128
#define WW 128

typedef short s8v __attribute__((ext_vector_type(8)));      // raw 16B move
typedef float f4v __attribute__((ext_vector_type(4)));      // 4 fp32 acc
typedef _Float16 h8 __attribute__((ext_vector_type(8)));    // 8 f16 (4 VGPRs)
typedef unsigned short u16;
typedef u16 u4v __attribute__((ext_vector_type(4)));

__device__ __forceinline__ u16 f2h(float f) {
    _Float16 h = (_Float16)f;
    return __builtin_bit_cast(u16, h);
}
__device__ __forceinline__ _Float16 h_from_bits(u16 b) {
    return __builtin_bit_cast(_Float16, b);
}

// ---------------------------------------------------------------------------
// Kernel 0: NCHW fp32 (x_vq ++ x_res) -> NHWC f16 xin[B][H][W][128]
// ---------------------------------------------------------------------------
__global__ __launch_bounds__(256)
void x2nhwc_kernel(const float* __restrict__ xvq, const float* __restrict__ xres,
                   u16* __restrict__ xout)
{
    const int h = blockIdx.x;
    const int b = blockIdx.y;
    __shared__ u16 lds[128 * 132];

    for (int i = 0; i < 16; ++i) {
        const int idx = threadIdx.x + 256 * i;       // 4096 float4
        const int c = idx >> 5;
        const int w4 = (idx & 31) * 4;
        const float* src = (c < 64)
            ? &xvq[(((size_t)b * 64 + c) * HH + h) * WW]
            : &xres[(((size_t)b * 64 + (c - 64)) * HH + h) * WW];
        const float4 v = *(const float4*)(src + w4);
        lds[(w4 + 0) * 132 + c] = f2h(v.x);
        lds[(w4 + 1) * 132 + c] = f2h(v.y);
        lds[(w4 + 2) * 132 + c] = f2h(v.z);
        lds[(w4 + 3) * 132 + c] = f2h(v.w);
    }
    __syncthreads();
    u16* orow = xout + (((size_t)b * HH + h) * WW) * 128;
    for (int i = 0; i < 16; ++i) {
        const int idx = threadIdx.x + 256 * i;       // 4096 ushort4
        const int w = idx >> 5;
        const int q = idx & 31;
        *(u4v*)(orow + (size_t)w * 128 + q * 4) = *(const u4v*)&lds[w * 132 + q * 4];
    }
}

// ---------------------------------------------------------------------------
// Fused weight transforms (fp32 -> f16).
// ---------------------------------------------------------------------------
__global__ void wfuse_kernel(const float* __restrict__ W1, const float* __restrict__ Woff,
                             const float* __restrict__ Wmod, const float* __restrict__ Wdcn,
                             u16* __restrict__ W1t, u16* __restrict__ Womt,
                             u16* __restrict__ Wdt)
{
    int idx = blockIdx.x * 256 + threadIdx.x;
    if (idx < 73728) {
        const int ic = idx & 127;
        const int oc = (idx >> 7) & 63;
        const int t  = idx >> 13;
        W1t[idx] = f2h(W1[((size_t)(oc * 128 + ic)) * 9 + t]);
        return;
    }
    idx -= 73728;
    if (idx < 18432) {
        const int c = idx & 63;
        const int o = (idx >> 6) & 31;
        const int t = idx >> 11;
        float v = 0.f;
        if (o < 18)      v = Woff[((size_t)(o * 64 + c)) * 9 + t];
        else if (o < 27) v = Wmod[((size_t)((o - 18) * 64 + c)) * 9 + t];
        Womt[idx] = f2h(v);
        return;
    }
    idx -= 18432;
    if (idx < 36864) {
        const int c  = idx & 63;
        const int oc = (idx >> 6) & 63;
        const int k  = idx >> 12;
        Wdt[idx] = f2h(Wdcn[((size_t)(oc * 64 + c)) * 9 + k]);
    }
}

// ---------------------------------------------------------------------------
// Kernel A: conv1 implicit-GEMM f16 MFMA (r5 version: weights staged in LDS —
// global loads inside the MFMA loop poison the vmcnt chain, measured r6).
// ---------------------------------------------------------------------------
__global__ __launch_bounds__(256)
void conv1_mfma_kernel(const u16* __restrict__ xin, const u16* __restrict__ W1t,
                       const float* __restrict__ b1, u16* __restrict__ feath)
{
    __shared__ u16 sTile[324 * 36];   // [18x18][ic32 pad36] 23.3 KB
    __shared__ u16 sW[576 * 36];      // [tap*64+oc][ic32 pad36] 41.5 KB

    const int x0 = blockIdx.x * 16;
    const int y0 = blockIdx.y * 16;
    const int b  = blockIdx.z;
    const int tid = threadIdx.x;
    const int lane = tid & 63;
    const int wave = tid >> 6;
    const int lm = lane & 15;
    const int kg = lane >> 4;

    const u16* xb = xin + ((size_t)b * HH * WW) * 128;

    f4v acc[4][4];
#pragma unroll
    for (int i = 0; i < 4; ++i)
#pragma unroll
        for (int j = 0; j < 4; ++j) acc[i][j] = (f4v)0.f;

    for (int chunk = 0; chunk < 4; ++chunk) {
        const int c0 = chunk * 32;
        __syncthreads();
        for (int i = 0; i < 6; ++i) {
            const int idx = tid + 256 * i;
            if (idx < 1296) {
                const int pix = idx >> 2;
                const int q   = idx & 3;
                const int gy = y0 - 1 + pix / 18;
                const int gx = x0 - 1 + pix % 18;
                s8v v = (s8v)0;
                if ((unsigned)gy < HH && (unsigned)gx < WW)
                    v = *(const s8v*)(xb + ((size_t)(gy * WW + gx)) * 128 + c0 + q * 8);
                *(s8v*)&sTile[pix * 36 + q * 8] = v;
            }
        }
        for (int i = 0; i < 9; ++i) {
            const int idx = tid + 256 * i;
            const int row = idx >> 2;      // t*64 + oc
            const int q   = idx & 3;
            *(s8v*)&sW[row * 36 + q * 8] =
                *(const s8v*)(W1t + (size_t)row * 128 + c0 + q * 8);
        }
        __syncthreads();

#pragma unroll
        for (int t = 0; t < 9; ++t) {
            const int dy = t / 3, dx = t % 3;
            h8 a[4], bq[4];
#pragma unroll
            for (int mt = 0; mt < 4; ++mt) {
                const int p = wave * 64 + mt * 16 + lm;
                const int sidx = ((p >> 4) + dy) * 18 + (p & 15) + dx;
                a[mt] = *(const h8*)&sTile[sidx * 36 + kg * 8];
            }
#pragma unroll
            for (int nt = 0; nt < 4; ++nt) {
                const int oc = nt * 16 + lm;
                bq[nt] = *(const h8*)&sW[(t * 64 + oc) * 36 + kg * 8];
            }
#pragma unroll
            for (int mt = 0; mt < 4; ++mt)
#pragma unroll
                for (int nt = 0; nt < 4; ++nt)
                    acc[mt][nt] = __builtin_amdgcn_mfma_f32_16x16x32_f16(
                        a[mt], bq[nt], acc[mt][nt], 0, 0, 0);
        }
    }

#pragma unroll
    for (int nt = 0; nt < 4; ++nt) {
        const int oc = nt * 16 + lm;
        const float bias = b1[oc];
#pragma unroll
        for (int mt = 0; mt < 4; ++mt)
#pragma unroll
            for (int r = 0; r < 4; ++r) {
                const int p = wave * 64 + mt * 16 + kg * 4 + r;
                const int y = y0 + (p >> 4), x = x0 + (p & 15);
                feath[(((size_t)b * HH + y) * WW + x) * CC + oc] =
                    f2h(acc[mt][nt][r] + bias);
            }
    }
}

// ---------------------------------------------------------------------------
// Kernel B: offset+mod conv (r5 version, LDS-staged weights).
// ---------------------------------------------------------------------------
__global__ __launch_bounds__(256)
void offmod_mfma_kernel(const u16* __restrict__ feath, const u16* __restrict__ Womt,
                        const float* __restrict__ boff, const float* __restrict__ bmod,
                        float* __restrict__ om)
{
    __shared__ u16 sTile[324 * 36];   // [18x18][c32 pad36] 23.3 KB
    __shared__ u16 sWom[288 * 36];    // [t*32+o][c32 pad36] 20.7 KB

    const int x0 = blockIdx.x * 16;
    const int y0 = blockIdx.y * 16;
    const int b  = blockIdx.z;
    const int tid = threadIdx.x;
    const int lane = tid & 63;
    const int wave = tid >> 6;
    const int lm = lane & 15;
    const int kg = lane >> 4;

    const u16* fb = feath + ((size_t)b * HH * WW) * CC;

    f4v acc[4][2];
#pragma unroll
    for (int i = 0; i < 4; ++i)
#pragma unroll
        for (int j = 0; j < 2; ++j) acc[i][j] = (f4v)0.f;

    for (int chunk = 0; chunk < 2; ++chunk) {
        const int c0 = chunk * 32;
        __syncthreads();
        for (int i = 0; i < 6; ++i) {
            const int idx = tid + 256 * i;
            if (idx < 1296) {
                const int pix = idx >> 2;
                const int q   = idx & 3;
                const int gy = y0 - 1 + pix / 18;
                const int gx = x0 - 1 + pix % 18;
                s8v v = (s8v)0;
                if ((unsigned)gy < HH && (unsigned)gx < WW)
                    v = *(const s8v*)(fb + ((size_t)(gy * WW + gx)) * CC + c0 + q * 8);
                *(s8v*)&sTile[pix * 36 + q * 8] = v;
            }
        }
        for (int i = 0; i < 5; ++i) {
            const int idx = tid + 256 * i;
            if (idx < 1152) {
                const int row = idx >> 2;     // t*32 + o
                const int q   = idx & 3;
                *(s8v*)&sWom[row * 36 + q * 8] =
                    *(const s8v*)(Womt + (size_t)row * 64 + c0 + q * 8);
            }
        }
        __syncthreads();

#pragma unroll
        for (int t = 0; t < 9; ++t) {
            const int dy = t / 3, dx = t % 3;
            h8 a[4], bq[2];
#pragma unroll
            for (int mt = 0; mt < 4; ++mt) {
                const int p = wave * 64 + mt * 16 + lm;
                const int sidx = ((p >> 4) + dy) * 18 + (p & 15) + dx;
                a[mt] = *(const h8*)&sTile[sidx * 36 + kg * 8];
            }
#pragma unroll
            for (int nt = 0; nt < 2; ++nt) {
                const int o = nt * 16 + lm;
                bq[nt] = *(const h8*)&sWom[(t * 32 + o) * 36 + kg * 8];
            }
#pragma unroll
            for (int mt = 0; mt < 4; ++mt)
#pragma unroll
                for (int nt = 0; nt < 2; ++nt)
                    acc[mt][nt] = __builtin_amdgcn_mfma_f32_16x16x32_f16(
                        a[mt], bq[nt], acc[mt][nt], 0, 0, 0);
        }
    }

#pragma unroll
    for (int nt = 0; nt < 2; ++nt) {
        const int o = nt * 16 + lm;
        if (o >= 27) continue;
#pragma unroll
        for (int mt = 0; mt < 4; ++mt)
#pragma unroll
            for (int r = 0; r < 4; ++r) {
                const int p = wave * 64 + mt * 16 + kg * 4 + r;
                const int y = y0 + (p >> 4), x = x0 + (p & 15);
                float* op = om + (((size_t)b * HH + y) * WW + x) * 27;
                if (o < 18) op[o] = acc[mt][nt][r] + boff[o];
                else {
                    const float z = acc[mt][nt][r] + bmod[o - 18];
                    op[o] = 2.f / (1.f + expf(-z));
                }
            }
    }
}

// ---------------------------------------------------------------------------
// Kernel C v3: deformable sampling + einsum. Records in REGISTERS (per-thread,
// all 9 taps). 3 taps per phase: 24 corner loads in flight, 2 barriers/phase
// (6 total vs 18). GEMM operands from LDS only (r6 lesson). K=192 per phase.
// ---------------------------------------------------------------------------
__global__ __launch_bounds__(256, 2)
void dcn_mfma_kernel(const u16* __restrict__ feath, const float* __restrict__ om,
                     const u16* __restrict__ Wdt, const float* __restrict__ bdcn,
                     float* __restrict__ out)
{
    __shared__ u16 sV[3][64 * 72];    // [tap][p][c64 pad72] 27.6 KB
    __shared__ u16 sWd[3][64 * 72];   // [tap][oc][c64 pad72] 27.6 KB
    __shared__ float sOm[64 * 28];    // [p][27 pad28] 7.2 KB   -> 62.4 KB total

    const int b  = blockIdx.z;
    const int x0 = blockIdx.x * 8;
    const int y0 = blockIdx.y * 8;
    const int tid = threadIdx.x;
    const int lane = tid & 63;
    const int wave = tid >> 6;
    const int wi = wave >> 1;
    const int wj = wave & 1;
    const int lm = lane & 15;
    const int kg = lane >> 4;

    for (int idx = tid; idx < 64 * 27; idx += 256) {
        const int p = idx / 27;
        const int j = idx - p * 27;
        const int y = y0 + (p >> 3), x = x0 + (p & 7);
        sOm[p * 28 + j] = om[(((size_t)b * HH + y) * WW + x) * 27 + j];
    }
    __syncthreads();

    const int p1 = tid >> 2;
    const int cb = (tid & 3) * 16;
    const int yy = y0 + (p1 >> 3);
    const int xx = x0 + (p1 & 7);

    // ---- per-thread bilinear records, all 9 taps (registers) ----
    int roff[9][4];
    u16 rwt[9][4];
#pragma unroll
    for (int k = 0; k < 9; ++k) {
        const float dy = sOm[p1 * 28 + 2 * k];
        const float dx = sOm[p1 * 28 + 2 * k + 1];
        const float m  = sOm[p1 * 28 + 18 + k];
        const float pyf = (float)(yy + (k / 3) - 1) + dy;
        const float pxf = (float)(xx + (k % 3) - 1) + dx;
        const float fy0 = floorf(pyf), fx0 = floorf(pxf);
        const float wy1 = pyf - fy0, wx1 = pxf - fx0;
        const int iy0 = (int)fy0, ix0 = (int)fx0;
        const float w[4] = { m * (1.f - wy1) * (1.f - wx1), m * (1.f - wy1) * wx1,
                             m * wy1 * (1.f - wx1),         m * wy1 * wx1 };
        const int ys[4] = { iy0, iy0, iy0 + 1, iy0 + 1 };
        const int xs[4] = { ix0, ix0 + 1, ix0, ix0 + 1 };
#pragma unroll
        for (int cn = 0; cn < 4; ++cn) {
            const bool valid = ((unsigned)ys[cn] < (unsigned)HH) &&
                               ((unsigned)xs[cn] < (unsigned)WW);
            roff[k][cn] = valid ? (ys[cn] * WW + xs[cn]) * CC : 0;
            rwt[k][cn]  = f2h(valid ? w[cn] : 0.f);
        }
    }

    f4v acc[2][2];
#pragma unroll
    for (int i = 0; i < 2; ++i)
#pragma unroll
        for (int j = 0; j < 2; ++j) acc[i][j] = (f4v)0.f;

    const u16* fb = feath + ((size_t)b * HH * WW) * CC;

    for (int ph = 0; ph < 3; ++ph) {
        __syncthreads();   // prev phase's sV/sWd reads complete

        // stage 3 taps' weights [oc][c] (L2-hot): 1536 x 16B
        for (int i = 0; i < 6; ++i) {
            const int idx = tid + 256 * i;
            const int t  = idx / 512;
            const int r  = idx & 511;
            const int oc = r >> 3, q = r & 7;
            *(s8v*)&sWd[t][oc * 72 + q * 8] =
                *(const s8v*)(Wdt + ((size_t)((ph * 3 + t) * 64 + oc)) * 64 + q * 8);
        }

        // gather: 24 corner loads in flight, then blend
        h8 cr[3][8];
#pragma unroll
        for (int t = 0; t < 3; ++t) {
            const int k = ph * 3 + t;
            const u16* c0p = fb + roff[k][0] + cb;
            const u16* c1p = fb + roff[k][1] + cb;
            const u16* c2p = fb + roff[k][2] + cb;
            const u16* c3p = fb + roff[k][3] + cb;
            cr[t][0] = *(const h8*)c0p; cr[t][1] = *(const h8*)(c0p + 8);
            cr[t][2] = *(const h8*)c1p; cr[t][3] = *(const h8*)(c1p + 8);
            cr[t][4] = *(const h8*)c2p; cr[t][5] = *(const h8*)(c2p + 8);
            cr[t][6] = *(const h8*)c3p; cr[t][7] = *(const h8*)(c3p + 8);
        }
#pragma unroll
        for (int t = 0; t < 3; ++t) {
            const int k = ph * 3 + t;
            h8 w8 = (h8)h_from_bits(rwt[k][0]);
            h8 a0 = w8 * cr[t][0];
            h8 a1 = w8 * cr[t][1];
            w8 = (h8)h_from_bits(rwt[k][1]);
            a0 += w8 * cr[t][2]; a1 += w8 * cr[t][3];
            w8 = (h8)h_from_bits(rwt[k][2]);
            a0 += w8 * cr[t][4]; a1 += w8 * cr[t][5];
            w8 = (h8)h_from_bits(rwt[k][3]);
            a0 += w8 * cr[t][6]; a1 += w8 * cr[t][7];
            *(h8*)&sV[t][p1 * 72 + cb]     = a0;
            *(h8*)&sV[t][p1 * 72 + cb + 8] = a1;
        }
        __syncthreads();

        // GEMM: acc += V[64p][192k] * Wd[192k][64oc], all from LDS
#pragma unroll
        for (int t = 0; t < 3; ++t) {
            h8 a[2][2], bf[2][2];
#pragma unroll
            for (int mt = 0; mt < 2; ++mt) {
                const int p = wi * 32 + mt * 16 + lm;
#pragma unroll
                for (int ks = 0; ks < 2; ++ks)
                    a[mt][ks] = *(const h8*)&sV[t][p * 72 + ks * 32 + kg * 8];
            }
#pragma unroll
            for (int nt = 0; nt < 2; ++nt) {
                const int oc = wj * 32 + nt * 16 + lm;
#pragma unroll
                for (int ks = 0; ks < 2; ++ks)
                    bf[nt][ks] = *(const h8*)&sWd[t][oc * 72 + ks * 32 + kg * 8];
            }
#pragma unroll
            for (int mt = 0; mt < 2; ++mt)
#pragma unroll
                for (int nt = 0; nt < 2; ++nt)
#pragma unroll
                    for (int ks = 0; ks < 2; ++ks)
                        acc[mt][nt] = __builtin_amdgcn_mfma_f32_16x16x32_f16(
                            a[mt][ks], bf[nt][ks], acc[mt][nt], 0, 0, 0);
        }
    }

    // epilogue: NCHW fp32
#pragma unroll
    for (int mt = 0; mt < 2; ++mt)
#pragma unroll
        for (int nt = 0; nt < 2; ++nt) {
            const int oc = wj * 32 + nt * 16 + lm;
            const float bias = bdcn[oc];
#pragma unroll
            for (int r = 0; r < 4; ++r) {
                const int p = wi * 32 + mt * 16 + kg * 4 + r;
                const int y = y0 + (p >> 3), x = x0 + (p & 7);
                out[(((size_t)b * CC + oc) * HH + y) * WW + x] = acc[mt][nt][r] + bias;
            }
        }
}

extern "C" void kernel_launch(void* const* d_in, const int* in_sizes, int n_in,
                              void* d_out, int out_size, void* d_ws, size_t ws_size,
                              hipStream_t stream)
{
    const float* xvq  = (const float*)d_in[0];
    const float* xres = (const float*)d_in[1];
    const float* W1   = (const float*)d_in[2];
    const float* b1   = (const float*)d_in[3];
    const float* Woff = (const float*)d_in[4];
    const float* boff = (const float*)d_in[5];
    const float* Wmod = (const float*)d_in[6];
    const float* bmod = (const float*)d_in[7];
    const float* Wdcn = (const float*)d_in[8];
    const float* bdcn = (const float*)d_in[9];
    float* out = (float*)d_out;

    u16*  feath = (u16*)d_ws;                              // 8.39M u16
    float* om   = (float*)(feath + (size_t)BB * HH * WW * CC);  // 3.54M f32
    u16*  xin   = (u16*)(om + (size_t)BB * HH * WW * 27);  // 16.78M u16
    u16*  W1t   = xin + (size_t)BB * HH * WW * 128;        // 73728 u16
    u16*  Womt  = W1t + 9 * 64 * 128;                      // 18432 u16
    u16*  Wdt   = Womt + 9 * 32 * 64;                      // 36864 u16

    x2nhwc_kernel<<<dim3(HH, BB), 256, 0, stream>>>(xvq, xres, xin);
    wfuse_kernel<<<dim3(504), 256, 0, stream>>>(W1, Woff, Wmod, Wdcn, W1t, Womt, Wdt);
    conv1_mfma_kernel<<<dim3(8, 8, 8), 256, 0, stream>>>(xin, W1t, b1, feath);
    offmod_mfma_kernel<<<dim3(8, 8, 8), 256, 0, stream>>>(feath, Womt, boff, bmod, om);
    dcn_mfma_kernel<<<dim3(16, 16, 8), 256, 0, stream>>>(feath, om, Wdt, bdcn, out);
}